// Round 14
// baseline (30.243 us; speedup 1.0000x reference)
//
#include <hip/hip_runtime.h>
#include <hip/hip_bf16.h>

#define TT 16384
#define BB 32

typedef __attribute__((ext_vector_type(8))) short bf16x8;
typedef __attribute__((ext_vector_type(4))) float f32x4;

#define S1 2.8853900817779268f   // 2*log2(e)

__device__ __forceinline__ unsigned short f2bf(float v) {   // prep only (verified)
    unsigned int u = __float_as_uint(v);
    u = (u + 0x7fffu + ((u >> 16) & 1u)) >> 16;   // RNE
    return (unsigned short)u;
}
// hot-path pack: per-element compiler cast (ROCm API); clang fuses pairs into
// v_cvt_pk_bf16_f32 (m240: compiler handles it; hand asm was the round-9 bug)
__device__ __forceinline__ unsigned int pk2(float lo, float hi) {
    __hip_bfloat16 a = __float2bfloat16(lo);
    __hip_bfloat16 b = __float2bfloat16(hi);
    union { __hip_bfloat16 h; unsigned short s; } ca, cb;
    ca.h = a; cb.h = b;
    return (unsigned)ca.s | ((unsigned)cb.s << 16);
}
__device__ __forceinline__ float rcore(float v) {   // r = 1/(exp2(v)+1); tanh = 1-2r folded downstream
    return __builtin_amdgcn_rcpf(__builtin_amdgcn_exp2f(v) + 1.0f);
}

// ---------------- preproc v2: byte-identical to round 12 (verified) ----------------
__global__ __launch_bounds__(256) void rvt_prep(
    const float* __restrict__ conv_w, const float* __restrict__ conv_b,
    const float* __restrict__ fc_hid_w, const float* __restrict__ fc_hid_b,
    const float* __restrict__ fc_out_w, const float* __restrict__ fc_out_b,
    unsigned int* __restrict__ wsu)
{
    __shared__ float Lfhw[576];
    __shared__ float Lcw[27], Lcb[3], Lfow[12], Lfob[2], Lfhb[6];
    const int tid = threadIdx.x;

    for (int i = tid; i < 576; i += 256) Lfhw[i] = fc_hid_w[i];
    if (tid < 27) Lcw[tid] = conv_w[tid];
    else if (tid < 30) Lcb[tid - 27] = conv_b[tid - 27];
    else if (tid < 42) Lfow[tid - 30] = fc_out_w[tid - 30];
    else if (tid < 44) Lfob[tid - 42] = fc_out_b[tid - 42];
    else if (tid < 50) Lfhb[tid - 44] = fc_hid_b[tid - 44];
    __syncthreads();

    if (tid < 64) {
        const int l = tid;
        const int m = l & 15, g = l >> 4;

        for (int mt = 0; mt < 3; ++mt)
            for (int kt = 0; kt < 2; ++kt) {
                unsigned short hs[8];
                #pragma unroll
                for (int e = 0; e < 8; ++e) {
                    int k = kt * 32 + g * 8 + e;
                    int r = k >> 4, hh = k & 15;
                    int kc = hh - m + 1;
                    float v = 0.f;
                    if (r < 3 && kc >= 0 && kc <= 2) v = S1 * Lcw[(mt * 3 + r) * 3 + kc];
                    hs[e] = f2bf(v);
                }
                int base = (mt * 2 + kt) * 256 + l * 4;
                wsu[base + 0] = hs[0] | ((unsigned)hs[1] << 16);
                wsu[base + 1] = hs[2] | ((unsigned)hs[3] << 16);
                wsu[base + 2] = hs[4] | ((unsigned)hs[5] << 16);
                wsu[base + 3] = hs[6] | ((unsigned)hs[7] << 16);
            }
        for (int kt = 0; kt < 3; ++kt) {
            unsigned short hs[8];
            #pragma unroll
            for (int e = 0; e < 8; ++e) {
                int q = kt * 32 + g * 8 + e;
                float v = 0.f;
                if (m < 6 && q < 96) {
                    int wr = (q >= 48) ? 1 : 0;
                    int col = q - 48 * wr;
                    int oc = col >> 4, c = col & 15;
                    v = -2.f * S1 * Lfhw[m * 96 + (oc * 2 + wr) * 16 + c];
                }
                hs[e] = f2bf(v);
            }
            int base = (6 + kt) * 256 + l * 4;
            wsu[base + 0] = hs[0] | ((unsigned)hs[1] << 16);
            wsu[base + 1] = hs[2] | ((unsigned)hs[3] << 16);
            wsu[base + 2] = hs[4] | ((unsigned)hs[5] << 16);
            wsu[base + 3] = hs[6] | ((unsigned)hs[7] << 16);
        }
        float* wsS = (float*)(wsu + 2304);
        if (l < 3) wsS[l] = S1 * Lcb[l];
        if (l < 6) {
            float s = Lfhb[l];
            #pragma unroll
            for (int i = 0; i < 96; ++i) s += Lfhw[l * 96 + i];
            wsS[3 + l] = S1 * s;
        }
        if (l < 2) {
            float s = Lfob[l];
            #pragma unroll
            for (int j = 0; j < 6; ++j) {
                float w = Lfow[l * 6 + j];
                s += w;
                wsS[9 + l * 6 + j] = -2.f * w;
            }
            wsS[21 + l] = s;
        }
    }
}

// ---------------- fused MFMA kernel: round-10 structure; pk2 now compiler cvt ----------------
// S: 68 rows x 32B/wave; physical 16B-half = logical ^ ((row>>2)&1)  (bank spread)
// G: plane-major, 6 planes x (65 cols x 16B)/wave; plane = feature/8
__device__ __forceinline__ void stage_row(char* S, const float* __restrict__ x,
                                          int b, int tb, int i) {
    const int trow = tb - 3 + i;
    uint4 h0 = {0u, 0u, 0u, 0u}, h1 = {0u, 0u, 0u, 0u};
    if (trow >= 0 && trow < TT) {
        const float4* p = (const float4*)x + (size_t)(b * TT + trow) * 4;
        float4 f0 = p[0], f1 = p[1], f2 = p[2], f3 = p[3];
        h0.x = pk2(f0.x, f0.y); h0.y = pk2(f0.z, f0.w);
        h0.z = pk2(f1.x, f1.y); h0.w = pk2(f1.z, f1.w);
        h1.x = pk2(f2.x, f2.y); h1.y = pk2(f2.z, f2.w);
        h1.z = pk2(f3.x, f3.y); h1.w = pk2(f3.z, f3.w);
    }
    const int s = (i >> 2) & 1;
    *(uint4*)(S + i * 32 + s * 16) = h0;          // logical half 0 (h=0..7)
    *(uint4*)(S + i * 32 + (s ^ 1) * 16) = h1;    // logical half 1 (h=8..15)
}

#define MFMA16(a, bb, cc) __builtin_amdgcn_mfma_f32_16x16x32_bf16((a), (bb), (cc), 0, 0, 0)
#define GPLANE 1040   // 65 cols * 16B

__global__ __launch_bounds__(256, 2) void rvt_mfma(
    const float* __restrict__ x, const uint4* __restrict__ wsA,
    const float* __restrict__ wsS, float* __restrict__ out)
{
    __shared__ __align__(16) char Sbuf[4 * 2176];
    __shared__ __align__(16) char Gbuf[4 * 6240];
    const int tid = threadIdx.x, wv = tid >> 6, l = tid & 63;
    const int n = l & 15, g = l >> 4;
    const int P0 = blockIdx.x << 8;           // 256 positions per block
    const int b  = P0 >> 14;                  // / TT
    const int tb = (P0 & (TT - 1)) + (wv << 6);

    char* S = Sbuf + wv * 2176;
    char* G = Gbuf + wv * 6240;

    // ---- stage x rows tb-3 .. tb+63 (67 rows) as bf16 ----
    stage_row(S, x, b, tb, l);
    if (l < 3) stage_row(S, x, b, tb, l + 64);

    // ---- A fragments (held in VGPRs for the whole kernel) ----
    union { uint4 u; bf16x8 f; } cv;
    bf16x8 A1[6], A2[3];
    #pragma unroll
    for (int i = 0; i < 6; ++i) { cv.u = wsA[i * 64 + l]; A1[i] = cv.f; }
    #pragma unroll
    for (int i = 0; i < 3; ++i) { cv.u = wsA[(6 + i) * 64 + l]; A2[i] = cv.f; }

    const float cbs0 = wsS[0], cbs1 = wsS[1], cbs2 = wsS[2];
    const int r0 = g * 4;
    const float b1i0 = (r0 + 0 < 6) ? wsS[3 + r0 + 0] : 0.f;
    const float b1i1 = (r0 + 1 < 6) ? wsS[3 + r0 + 1] : 0.f;
    const float b1i2 = (r0 + 2 < 6) ? wsS[3 + r0 + 2] : 0.f;
    const float b1i3 = (r0 + 3 < 6) ? wsS[3 + r0 + 3] : 0.f;
    const float w200 = wsS[9],  w201 = wsS[10], w202 = wsS[11];
    const float w203 = wsS[12], w204 = wsS[13], w205 = wsS[14];
    const float w210 = wsS[15], w211 = wsS[16], w212 = wsS[17];
    const float w213 = wsS[18], w214 = wsS[19], w215 = wsS[20];
    const float b2s0 = wsS[21], b2s1 = wsS[22];

    #pragma unroll
    for (int p = 0; p <= 4; ++p) {
        // ===== MFMA1: conv for G-columns 16p..16p+15 =====
        const int ra = 16 * p + n + (g >> 1);
        bf16x8 bk0 = *(const bf16x8*)(S + ra * 32 + (((g & 1) ^ ((ra >> 2) & 1)) << 4));
        bf16x8 bk1 = {0, 0, 0, 0, 0, 0, 0, 0};
        if (g < 2) {
            const int rb = 16 * p + n + 2;
            bk1 = *(const bf16x8*)(S + rb * 32 + ((g ^ ((rb >> 2) & 1)) << 4));
        }

        f32x4 ac0 = {cbs0, cbs0, cbs0, cbs0};
        f32x4 ac1 = {cbs1, cbs1, cbs1, cbs1};
        f32x4 ac2 = {cbs2, cbs2, cbs2, cbs2};
        ac0 = MFMA16(A1[0], bk0, ac0); ac0 = MFMA16(A1[1], bk1, ac0);
        ac1 = MFMA16(A1[2], bk0, ac1); ac1 = MFMA16(A1[3], bk1, ac1);
        ac2 = MFMA16(A1[4], bk0, ac2); ac2 = MFMA16(A1[5], bk1, ac2);

        if (p < 4 || n == 0) {          // p=4 computes only the 65th column
            // feature q = oc*16 + g*4 + i ; plane = 2*oc + (g>>1) ; byte (g&1)*8
            char* gc = G + (16 * p + n) * 16 + ((g & 1) << 3) + ((g >> 1) ? GPLANE : 0);
            {
                uint2 w;
                w.x = pk2(rcore(ac0.x), rcore(ac0.y));
                w.y = pk2(rcore(ac0.z), rcore(ac0.w));
                *(uint2*)(gc + 0 * GPLANE) = w;
            }
            {
                uint2 w;
                w.x = pk2(rcore(ac1.x), rcore(ac1.y));
                w.y = pk2(rcore(ac1.z), rcore(ac1.w));
                *(uint2*)(gc + 2 * GPLANE) = w;
            }
            {
                uint2 w;
                w.x = pk2(rcore(ac2.x), rcore(ac2.y));
                w.y = pk2(rcore(ac2.z), rcore(ac2.w));
                *(uint2*)(gc + 4 * GPLANE) = w;
            }
        }

        // ===== MFMA2: FC1+FC2 for position tile p2=p-1 =====
        if (p >= 1) {
            const int p2 = p - 1;
            const int c0 = 16 * p2 + n;
            bf16x8 B0 = *(const bf16x8*)(G + g * GPLANE + c0 * 16);
            bf16x8 B1 = (g < 2)
                ? *(const bf16x8*)(G + (4 + g) * GPLANE + c0 * 16)
                : *(const bf16x8*)(G + (g - 2) * GPLANE + (c0 + 1) * 16);
            bf16x8 B2 = *(const bf16x8*)(G + (2 + g) * GPLANE + (c0 + 1) * 16);
            f32x4 h = {b1i0, b1i1, b1i2, b1i3};
            h = MFMA16(A2[0], B0, h);
            h = MFMA16(A2[1], B1, h);
            h = MFMA16(A2[2], B2, h);
            float r20 = rcore(h.x), r21 = rcore(h.y), r22 = rcore(h.z), r23 = rcore(h.w);
            float u0 = __shfl(r20, n + 16, 64);
            float u1 = __shfl(r21, n + 16, 64);
            float y0 = b2s0 + w200 * r20 + w201 * r21 + w202 * r22 + w203 * r23
                            + w204 * u0 + w205 * u1;
            float y1 = b2s1 + w210 * r20 + w211 * r21 + w212 * r22 + w213 * r23
                            + w214 * u0 + w215 * u1;
            if (l < 16)
                reinterpret_cast<float2*>(out)[(size_t)b * TT + tb + 16 * p2 + n] =
                    make_float2(y0, y1);
        }
    }
}

extern "C" void kernel_launch(void* const* d_in, const int* in_sizes, int n_in,
                              void* d_out, int out_size, void* d_ws, size_t ws_size,
                              hipStream_t stream) {
    const float* x        = (const float*)d_in[0];
    const float* conv_w   = (const float*)d_in[1];
    const float* conv_b   = (const float*)d_in[2];
    const float* fc_hid_w = (const float*)d_in[3];
    const float* fc_hid_b = (const float*)d_in[4];
    const float* fc_out_w = (const float*)d_in[5];
    const float* fc_out_b = (const float*)d_in[6];
    float* out = (float*)d_out;
    unsigned int* wsu = (unsigned int*)d_ws;

    rvt_prep<<<1, 256, 0, stream>>>(conv_w, conv_b, fc_hid_w, fc_hid_b,
                                    fc_out_w, fc_out_b, wsu);

    const int grid = (BB * TT) / 256;   // 2048 blocks, 256 positions each
    rvt_mfma<<<grid, 256, 0, stream>>>(x, (const uint4*)d_ws,
                                       (const float*)d_ws + 2304, out);
}

// Round 15
// 30.110 us; speedup vs baseline: 1.0044x; 1.0044x over previous
//
#include <hip/hip_runtime.h>

#define TT 16384
#define BB 32

typedef __attribute__((ext_vector_type(8))) short bf16x8;
typedef __attribute__((ext_vector_type(4))) float f32x4;

#define S1 2.8853900817779268f   // 2*log2(e)

__device__ __forceinline__ unsigned short f2bf(float v) {
    unsigned int u = __float_as_uint(v);
    u = (u + 0x7fffu + ((u >> 16) & 1u)) >> 16;   // RNE
    return (unsigned short)u;
}
__device__ __forceinline__ unsigned int pk2(float lo, float hi) {
    return (unsigned)f2bf(lo) | ((unsigned)f2bf(hi) << 16);
}
__device__ __forceinline__ float rcore(float v) {   // r = 1/(exp2(v)+1); tanh = 1-2r folded downstream
    return __builtin_amdgcn_rcpf(__builtin_amdgcn_exp2f(v) + 1.0f);
}

// ---------------- preproc: byte-identical to round 12 (verified) ----------------
__global__ __launch_bounds__(256) void rvt_prep(
    const float* __restrict__ conv_w, const float* __restrict__ conv_b,
    const float* __restrict__ fc_hid_w, const float* __restrict__ fc_hid_b,
    const float* __restrict__ fc_out_w, const float* __restrict__ fc_out_b,
    unsigned int* __restrict__ wsu)
{
    __shared__ float Lfhw[576];
    __shared__ float Lcw[27], Lcb[3], Lfow[12], Lfob[2], Lfhb[6];
    const int tid = threadIdx.x;

    for (int i = tid; i < 576; i += 256) Lfhw[i] = fc_hid_w[i];
    if (tid < 27) Lcw[tid] = conv_w[tid];
    else if (tid < 30) Lcb[tid - 27] = conv_b[tid - 27];
    else if (tid < 42) Lfow[tid - 30] = fc_out_w[tid - 30];
    else if (tid < 44) Lfob[tid - 42] = fc_out_b[tid - 42];
    else if (tid < 50) Lfhb[tid - 44] = fc_hid_b[tid - 44];
    __syncthreads();

    if (tid < 64) {
        const int l = tid;
        const int m = l & 15, g = l >> 4;

        for (int mt = 0; mt < 3; ++mt)
            for (int kt = 0; kt < 2; ++kt) {
                unsigned short hs[8];
                #pragma unroll
                for (int e = 0; e < 8; ++e) {
                    int k = kt * 32 + g * 8 + e;
                    int r = k >> 4, hh = k & 15;
                    int kc = hh - m + 1;
                    float v = 0.f;
                    if (r < 3 && kc >= 0 && kc <= 2) v = S1 * Lcw[(mt * 3 + r) * 3 + kc];
                    hs[e] = f2bf(v);
                }
                int base = (mt * 2 + kt) * 256 + l * 4;
                wsu[base + 0] = hs[0] | ((unsigned)hs[1] << 16);
                wsu[base + 1] = hs[2] | ((unsigned)hs[3] << 16);
                wsu[base + 2] = hs[4] | ((unsigned)hs[5] << 16);
                wsu[base + 3] = hs[6] | ((unsigned)hs[7] << 16);
            }
        for (int kt = 0; kt < 3; ++kt) {
            unsigned short hs[8];
            #pragma unroll
            for (int e = 0; e < 8; ++e) {
                int q = kt * 32 + g * 8 + e;
                float v = 0.f;
                if (m < 6 && q < 96) {
                    int wr = (q >= 48) ? 1 : 0;
                    int col = q - 48 * wr;
                    int oc = col >> 4, c = col & 15;
                    v = -2.f * S1 * Lfhw[m * 96 + (oc * 2 + wr) * 16 + c];
                }
                hs[e] = f2bf(v);
            }
            int base = (6 + kt) * 256 + l * 4;
            wsu[base + 0] = hs[0] | ((unsigned)hs[1] << 16);
            wsu[base + 1] = hs[2] | ((unsigned)hs[3] << 16);
            wsu[base + 2] = hs[4] | ((unsigned)hs[5] << 16);
            wsu[base + 3] = hs[6] | ((unsigned)hs[7] << 16);
        }
        float* wsS = (float*)(wsu + 2304);
        if (l < 3) wsS[l] = S1 * Lcb[l];
        if (l < 6) {
            float s = Lfhb[l];
            #pragma unroll
            for (int i = 0; i < 96; ++i) s += Lfhw[l * 96 + i];
            wsS[3 + l] = S1 * s;
        }
        if (l < 2) {
            float s = Lfob[l];
            #pragma unroll
            for (int j = 0; j < 6; ++j) {
                float w = Lfow[l * 6 + j];
                s += w;
                wsS[9 + l * 6 + j] = -2.f * w;
            }
            wsS[21 + l] = s;
        }
    }
}

// ---------------- fused MFMA kernel: ring LDS (round-11-verified addressing),
// ROLLED p-loop + __launch_bounds__(256,4) to cut VGPR pressure -> 4 waves/SIMD ----------------
// S: 64-row ring x 32B; slot = row&63; physical 16B-half = logical ^ ((row>>2)&1)
// G: 2-tile ring, 6 planes x 32 cols x 16B; slot = col&31
__device__ __forceinline__ void stage_row(char* S, const float* __restrict__ x,
                                          int b, int tb, int i) {
    const int trow = tb - 3 + i;
    uint4 h0 = {0u, 0u, 0u, 0u}, h1 = {0u, 0u, 0u, 0u};
    if (trow >= 0 && trow < TT) {
        const float4* p = (const float4*)x + (size_t)(b * TT + trow) * 4;
        float4 f0 = p[0], f1 = p[1], f2 = p[2], f3 = p[3];
        h0.x = pk2(f0.x, f0.y); h0.y = pk2(f0.z, f0.w);
        h0.z = pk2(f1.x, f1.y); h0.w = pk2(f1.z, f1.w);
        h1.x = pk2(f2.x, f2.y); h1.y = pk2(f2.z, f2.w);
        h1.z = pk2(f3.x, f3.y); h1.w = pk2(f3.z, f3.w);
    }
    const int s = (i >> 2) & 1;
    char* base = S + (i & 63) * 32;
    *(uint4*)(base + s * 16) = h0;          // logical half 0 (h=0..7)
    *(uint4*)(base + (s ^ 1) * 16) = h1;    // logical half 1 (h=8..15)
}

#define MFMA16(a, bb, cc) __builtin_amdgcn_mfma_f32_16x16x32_bf16((a), (bb), (cc), 0, 0, 0)
#define GPLANE 512   // 32 cols * 16B

__global__ __launch_bounds__(256, 4) void rvt_mfma(
    const float* __restrict__ x, const uint4* __restrict__ wsA,
    const float* __restrict__ wsS, float* __restrict__ out)
{
    __shared__ __align__(16) char Sbuf[4 * 2048];
    __shared__ __align__(16) char Gbuf[4 * 3072];
    const int tid = threadIdx.x, wv = tid >> 6, l = tid & 63;
    const int n = l & 15, g = l >> 4;
    const int P0 = blockIdx.x << 8;           // 256 positions per block
    const int b  = P0 >> 14;                  // / TT
    const int tb = (P0 & (TT - 1)) + (wv << 6);

    char* S = Sbuf + wv * 2048;
    char* G = Gbuf + wv * 3072;

    // ---- prologue: stage x rows 0..63 (rows tb-3 .. tb+60) ----
    stage_row(S, x, b, tb, l);

    // ---- A fragments (held in VGPRs for the whole kernel) ----
    union { uint4 u; bf16x8 f; } cv;
    bf16x8 A1[6], A2[3];
    #pragma unroll
    for (int i = 0; i < 6; ++i) { cv.u = wsA[i * 64 + l]; A1[i] = cv.f; }
    #pragma unroll
    for (int i = 0; i < 3; ++i) { cv.u = wsA[(6 + i) * 64 + l]; A2[i] = cv.f; }

    const float cbs0 = wsS[0], cbs1 = wsS[1], cbs2 = wsS[2];
    const int r0 = g * 4;
    const float b1i0 = (r0 + 0 < 6) ? wsS[3 + r0 + 0] : 0.f;
    const float b1i1 = (r0 + 1 < 6) ? wsS[3 + r0 + 1] : 0.f;
    const float b1i2 = (r0 + 2 < 6) ? wsS[3 + r0 + 2] : 0.f;
    const float b1i3 = (r0 + 3 < 6) ? wsS[3 + r0 + 3] : 0.f;
    const float w200 = wsS[9],  w201 = wsS[10], w202 = wsS[11];
    const float w203 = wsS[12], w204 = wsS[13], w205 = wsS[14];
    const float w210 = wsS[15], w211 = wsS[16], w212 = wsS[17];
    const float w213 = wsS[18], w214 = wsS[19], w215 = wsS[20];
    const float b2s0 = wsS[21], b2s1 = wsS[22];

    #pragma clang loop unroll(disable)
    for (int p = 0; p <= 4; ++p) {
        // tail rows 64..66 staged after p=0's reads (slots 0..2; rows 0..2 dead)
        if (p == 1 && l < 3) stage_row(S, x, b, tb, l + 64);

        // ===== MFMA1: conv for G-columns 16p..16p+15 =====
        const int ra = 16 * p + n + (g >> 1);
        bf16x8 bk0 = *(const bf16x8*)(S + (ra & 63) * 32 + (((g & 1) ^ ((ra >> 2) & 1)) << 4));
        bf16x8 bk1 = {0, 0, 0, 0, 0, 0, 0, 0};
        if (g < 2) {
            const int rb = 16 * p + n + 2;
            bk1 = *(const bf16x8*)(S + (rb & 63) * 32 + ((g ^ ((rb >> 2) & 1)) << 4));
        }

        f32x4 ac0 = {cbs0, cbs0, cbs0, cbs0};
        f32x4 ac1 = {cbs1, cbs1, cbs1, cbs1};
        f32x4 ac2 = {cbs2, cbs2, cbs2, cbs2};
        ac0 = MFMA16(A1[0], bk0, ac0); ac0 = MFMA16(A1[1], bk1, ac0);
        ac1 = MFMA16(A1[2], bk0, ac1); ac1 = MFMA16(A1[3], bk1, ac1);
        ac2 = MFMA16(A1[4], bk0, ac2); ac2 = MFMA16(A1[5], bk1, ac2);

        if (p < 4 || n == 0) {          // p=4 computes only column 64 (ring slot 0)
            // feature q = oc*16 + g*4 + i ; plane = 2*oc + (g>>1) ; byte (g&1)*8
            char* gc = G + ((16 * p + n) & 31) * 16 + ((g & 1) << 3) + ((g >> 1) ? GPLANE : 0);
            {
                uint2 w;
                w.x = pk2(rcore(ac0.x), rcore(ac0.y));
                w.y = pk2(rcore(ac0.z), rcore(ac0.w));
                *(uint2*)(gc + 0 * GPLANE) = w;
            }
            {
                uint2 w;
                w.x = pk2(rcore(ac1.x), rcore(ac1.y));
                w.y = pk2(rcore(ac1.z), rcore(ac1.w));
                *(uint2*)(gc + 2 * GPLANE) = w;
            }
            {
                uint2 w;
                w.x = pk2(rcore(ac2.x), rcore(ac2.y));
                w.y = pk2(rcore(ac2.z), rcore(ac2.w));
                *(uint2*)(gc + 4 * GPLANE) = w;
            }
        }

        // ===== MFMA2: FC1+FC2 for position tile p2=p-1 =====
        if (p >= 1) {
            const int p2 = p - 1;
            const int c0 = 16 * p2 + n;
            bf16x8 B0 = *(const bf16x8*)(G + g * GPLANE + (c0 & 31) * 16);
            bf16x8 B1 = (g < 2)
                ? *(const bf16x8*)(G + (4 + g) * GPLANE + (c0 & 31) * 16)
                : *(const bf16x8*)(G + (g - 2) * GPLANE + ((c0 + 1) & 31) * 16);
            bf16x8 B2 = *(const bf16x8*)(G + (2 + g) * GPLANE + ((c0 + 1) & 31) * 16);
            f32x4 h = {b1i0, b1i1, b1i2, b1i3};
            h = MFMA16(A2[0], B0, h);
            h = MFMA16(A2[1], B1, h);
            h = MFMA16(A2[2], B2, h);
            float r20 = rcore(h.x), r21 = rcore(h.y), r22 = rcore(h.z), r23 = rcore(h.w);
            float u0 = __shfl(r20, n + 16, 64);
            float u1 = __shfl(r21, n + 16, 64);
            float y0 = b2s0 + w200 * r20 + w201 * r21 + w202 * r22 + w203 * r23
                            + w204 * u0 + w205 * u1;
            float y1 = b2s1 + w210 * r20 + w211 * r21 + w212 * r22 + w213 * r23
                            + w214 * u0 + w215 * u1;
            if (l < 16)
                reinterpret_cast<float2*>(out)[(size_t)b * TT + tb + 16 * p2 + n] =
                    make_float2(y0, y1);
        }
    }
}

extern "C" void kernel_launch(void* const* d_in, const int* in_sizes, int n_in,
                              void* d_out, int out_size, void* d_ws, size_t ws_size,
                              hipStream_t stream) {
    const float* x        = (const float*)d_in[0];
    const float* conv_w   = (const float*)d_in[1];
    const float* conv_b   = (const float*)d_in[2];
    const float* fc_hid_w = (const float*)d_in[3];
    const float* fc_hid_b = (const float*)d_in[4];
    const float* fc_out_w = (const float*)d_in[5];
    const float* fc_out_b = (const float*)d_in[6];
    float* out = (float*)d_out;
    unsigned int* wsu = (unsigned int*)d_ws;

    rvt_prep<<<1, 256, 0, stream>>>(conv_w, conv_b, fc_hid_w, fc_hid_b,
                                    fc_out_w, fc_out_b, wsu);

    const int grid = (BB * TT) / 256;   // 2048 blocks, 256 positions each
    rvt_mfma<<<grid, 256, 0, stream>>>(x, (const uint4*)d_ws,
                                       (const float*)d_ws + 2304, out);
}

// Round 16
// 27.767 us; speedup vs baseline: 1.0892x; 1.0844x over previous
//
#include <hip/hip_runtime.h>

#define TT 16384
#define BB 32

typedef __attribute__((ext_vector_type(8))) short bf16x8;
typedef __attribute__((ext_vector_type(4))) float f32x4;

#define S1 2.8853900817779268f   // 2*log2(e)

__device__ __forceinline__ unsigned short f2bf(float v) {
    unsigned int u = __float_as_uint(v);
    u = (u + 0x7fffu + ((u >> 16) & 1u)) >> 16;   // RNE
    return (unsigned short)u;
}
__device__ __forceinline__ unsigned int pk2(float lo, float hi) {
    return (unsigned)f2bf(lo) | ((unsigned)f2bf(hi) << 16);
}
__device__ __forceinline__ float rcore(float v) {   // r = 1/(exp2(v)+1); tanh = 1-2r
    return __builtin_amdgcn_rcpf(__builtin_amdgcn_exp2f(v) + 1.0f);
}

// ---------------- single fused kernel ----------------
// Weight prep folded into every block (no reductions formulation):
//   G stores t = tanh directly; A2 = S1*W1 (raw), bias = S1*b1, FC2 uses raw w2.
// CwPad[(mt*4+r)*48 + kc+14] = S1*conv_w (zeros elsewhere; row r=3 all zero)
//   -> A1 gather: 8 consecutive scalar reads, no branches, OOB taps read 0.
// FhwPad[m*96 + i] = S1*fc_hid_w[m*96+i] (m<6) -> each A2 half = aligned b128.
// S: 68 rows x 32B/wave; physical 16B-half = logical ^ ((row>>2)&1)
// G: plane-major, 6 planes x (65 cols x 16B)/wave
__device__ __forceinline__ void stage_row(char* S, const float* __restrict__ x,
                                          int b, int tb, int i) {
    const int trow = tb - 3 + i;
    uint4 h0 = {0u, 0u, 0u, 0u}, h1 = {0u, 0u, 0u, 0u};
    if (trow >= 0 && trow < TT) {
        const float4* p = (const float4*)x + (size_t)(b * TT + trow) * 4;
        float4 f0 = p[0], f1 = p[1], f2 = p[2], f3 = p[3];
        h0.x = pk2(f0.x, f0.y); h0.y = pk2(f0.z, f0.w);
        h0.z = pk2(f1.x, f1.y); h0.w = pk2(f1.z, f1.w);
        h1.x = pk2(f2.x, f2.y); h1.y = pk2(f2.z, f2.w);
        h1.z = pk2(f3.x, f3.y); h1.w = pk2(f3.z, f3.w);
    }
    const int s = (i >> 2) & 1;
    *(uint4*)(S + i * 32 + s * 16) = h0;
    *(uint4*)(S + i * 32 + (s ^ 1) * 16) = h1;
}

#define MFMA16(a, bb, cc) __builtin_amdgcn_mfma_f32_16x16x32_bf16((a), (bb), (cc), 0, 0, 0)
#define GPLANE 1040   // 65 cols * 16B

__global__ __launch_bounds__(256, 2) void rvt_one(
    const float* __restrict__ x,
    const float* __restrict__ conv_w, const float* __restrict__ conv_b,
    const float* __restrict__ fc_hid_w, const float* __restrict__ fc_hid_b,
    const float* __restrict__ fc_out_w, const float* __restrict__ fc_out_b,
    float* __restrict__ out)
{
    __shared__ __align__(16) char Sbuf[4 * 2176];
    __shared__ __align__(16) char Gbuf[4 * 6240];
    __shared__ __align__(16) float CwPad[576];    // [mt*4+r][48], S1-scaled
    __shared__ __align__(16) float FhwPad[576];   // [m<6][96], S1-scaled
    __shared__ float Small[23];                   // [0..2]=S1*cb [3..8]=S1*b1 [9..20]=w2 [21..22]=b2

    const int tid = threadIdx.x, wv = tid >> 6, l = tid & 63;
    const int n = l & 15, g = l >> 4;
    const int m = n;                              // A-row index (conv col / fc1 row)
    const int P0 = blockIdx.x << 8;
    const int b  = P0 >> 14;
    const int tb = (P0 & (TT - 1)) + (wv << 6);

    char* S = Sbuf + wv * 2176;
    char* G = Gbuf + wv * 6240;

    // ---- stage x rows (per-wave, overlaps with pad build) ----
    stage_row(S, x, b, tb, l);
    if (l < 3) stage_row(S, x, b, tb, l + 64);

    // ---- build pre-scaled weight tables (block-cooperative, coalesced) ----
    for (int i = tid; i < 576; i += 256) FhwPad[i] = S1 * fc_hid_w[i];
    for (int s = tid; s < 576; s += 256) {
        const int r = (s / 48) & 3, kcp = s % 48;
        if (!(r < 3 && kcp >= 14 && kcp <= 16)) CwPad[s] = 0.f;
    }
    if (tid < 27) {
        const int mt = tid / 9, r = (tid % 9) / 3, kc = tid % 3;
        CwPad[(mt * 4 + r) * 48 + 14 + kc] = S1 * conv_w[tid];
    } else if (tid < 30) Small[tid - 27] = S1 * conv_b[tid - 27];
    else if (tid < 36) Small[3 + tid - 30] = S1 * fc_hid_b[tid - 30];
    else if (tid < 48) Small[9 + tid - 36] = fc_out_w[tid - 36];
    else if (tid < 50) Small[21 + tid - 48] = fc_out_b[tid - 48];
    __syncthreads();

    // ---- per-lane A-fragment gather from LDS ----
    union { uint4 u; bf16x8 f; } cv;
    bf16x8 A1[6], A2[3];
    #pragma unroll
    for (int mt = 0; mt < 3; ++mt)
        #pragma unroll
        for (int kt = 0; kt < 2; ++kt) {
            const int rr = kt * 2 + (g >> 1);
            const float* p = &CwPad[(mt * 4 + rr) * 48 + ((g & 1) * 8 - m + 15)];
            cv.u.x = pk2(p[0], p[1]);
            cv.u.y = pk2(p[2], p[3]);
            cv.u.z = pk2(p[4], p[5]);
            cv.u.w = pk2(p[6], p[7]);
            A1[mt * 2 + kt] = cv.f;
        }
    {
        const unsigned umask = (m < 6) ? 0xFFFFFFFFu : 0u;
        const int mc = (m < 6) ? m : 5;
        #pragma unroll
        for (int kt2 = 0; kt2 < 3; ++kt2) {
            const int q0 = kt2 * 32 + g * 8;
            const int wr = (q0 >= 48) ? 1 : 0;
            const int col0 = q0 - 48 * wr;
            const int oc = col0 >> 4, c0 = col0 & 15;
            const float4* fp = (const float4*)&FhwPad[mc * 96 + (oc * 2 + wr) * 16 + c0];
            float4 a = fp[0], bq = fp[1];
            cv.u.x = pk2(a.x, a.y) & umask;
            cv.u.y = pk2(a.z, a.w) & umask;
            cv.u.z = pk2(bq.x, bq.y) & umask;
            cv.u.w = pk2(bq.z, bq.w) & umask;
            A2[kt2] = cv.f;
        }
    }

    const float cbs0 = Small[0], cbs1 = Small[1], cbs2 = Small[2];
    const int r0 = g * 4;
    const float b1i0 = (r0 + 0 < 6) ? Small[3 + r0 + 0] : 0.f;
    const float b1i1 = (r0 + 1 < 6) ? Small[3 + r0 + 1] : 0.f;
    const float b1i2 = (r0 + 2 < 6) ? Small[3 + r0 + 2] : 0.f;
    const float b1i3 = (r0 + 3 < 6) ? Small[3 + r0 + 3] : 0.f;
    const float w200 = Small[9],  w201 = Small[10], w202 = Small[11];
    const float w203 = Small[12], w204 = Small[13], w205 = Small[14];
    const float w210 = Small[15], w211 = Small[16], w212 = Small[17];
    const float w213 = Small[18], w214 = Small[19], w215 = Small[20];
    const float b2s0 = Small[21], b2s1 = Small[22];

    #pragma unroll
    for (int p = 0; p <= 4; ++p) {
        // ===== MFMA1: conv for G-columns 16p..16p+15 =====
        const int ra = 16 * p + n + (g >> 1);
        bf16x8 bk0 = *(const bf16x8*)(S + ra * 32 + (((g & 1) ^ ((ra >> 2) & 1)) << 4));
        bf16x8 bk1 = {0, 0, 0, 0, 0, 0, 0, 0};
        if (g < 2) {
            const int rb = 16 * p + n + 2;
            bk1 = *(const bf16x8*)(S + rb * 32 + ((g ^ ((rb >> 2) & 1)) << 4));
        }

        f32x4 ac0 = {cbs0, cbs0, cbs0, cbs0};
        f32x4 ac1 = {cbs1, cbs1, cbs1, cbs1};
        f32x4 ac2 = {cbs2, cbs2, cbs2, cbs2};
        ac0 = MFMA16(A1[0], bk0, ac0); ac0 = MFMA16(A1[1], bk1, ac0);
        ac1 = MFMA16(A1[2], bk0, ac1); ac1 = MFMA16(A1[3], bk1, ac1);
        ac2 = MFMA16(A1[4], bk0, ac2); ac2 = MFMA16(A1[5], bk1, ac2);

        if (p < 4 || n == 0) {
            // G stores t = tanh = 1 - 2*r directly
            char* gc = G + (16 * p + n) * 16 + ((g & 1) << 3) + ((g >> 1) ? GPLANE : 0);
            {
                uint2 w;
                w.x = pk2(fmaf(-2.f, rcore(ac0.x), 1.f), fmaf(-2.f, rcore(ac0.y), 1.f));
                w.y = pk2(fmaf(-2.f, rcore(ac0.z), 1.f), fmaf(-2.f, rcore(ac0.w), 1.f));
                *(uint2*)(gc + 0 * GPLANE) = w;
            }
            {
                uint2 w;
                w.x = pk2(fmaf(-2.f, rcore(ac1.x), 1.f), fmaf(-2.f, rcore(ac1.y), 1.f));
                w.y = pk2(fmaf(-2.f, rcore(ac1.z), 1.f), fmaf(-2.f, rcore(ac1.w), 1.f));
                *(uint2*)(gc + 2 * GPLANE) = w;
            }
            {
                uint2 w;
                w.x = pk2(fmaf(-2.f, rcore(ac2.x), 1.f), fmaf(-2.f, rcore(ac2.y), 1.f));
                w.y = pk2(fmaf(-2.f, rcore(ac2.z), 1.f), fmaf(-2.f, rcore(ac2.w), 1.f));
                *(uint2*)(gc + 4 * GPLANE) = w;
            }
        }

        // ===== MFMA2: FC1+FC2 for position tile p2=p-1 =====
        if (p >= 1) {
            const int p2 = p - 1;
            const int c0 = 16 * p2 + n;
            bf16x8 B0 = *(const bf16x8*)(G + g * GPLANE + c0 * 16);
            bf16x8 B1 = (g < 2)
                ? *(const bf16x8*)(G + (4 + g) * GPLANE + c0 * 16)
                : *(const bf16x8*)(G + (g - 2) * GPLANE + (c0 + 1) * 16);
            bf16x8 B2 = *(const bf16x8*)(G + (2 + g) * GPLANE + (c0 + 1) * 16);
            f32x4 h = {b1i0, b1i1, b1i2, b1i3};
            h = MFMA16(A2[0], B0, h);
            h = MFMA16(A2[1], B1, h);
            h = MFMA16(A2[2], B2, h);
            float t20 = fmaf(-2.f, rcore(h.x), 1.f);
            float t21 = fmaf(-2.f, rcore(h.y), 1.f);
            float t22 = fmaf(-2.f, rcore(h.z), 1.f);
            float t23 = fmaf(-2.f, rcore(h.w), 1.f);
            float u0 = __shfl(t20, n + 16, 64);
            float u1 = __shfl(t21, n + 16, 64);
            float y0 = b2s0 + w200 * t20 + w201 * t21 + w202 * t22 + w203 * t23
                            + w204 * u0 + w205 * u1;
            float y1 = b2s1 + w210 * t20 + w211 * t21 + w212 * t22 + w213 * t23
                            + w214 * u0 + w215 * u1;
            if (l < 16)
                reinterpret_cast<float2*>(out)[(size_t)b * TT + tb + 16 * p2 + n] =
                    make_float2(y0, y1);
        }
    }
}

extern "C" void kernel_launch(void* const* d_in, const int* in_sizes, int n_in,
                              void* d_out, int out_size, void* d_ws, size_t ws_size,
                              hipStream_t stream) {
    const float* x        = (const float*)d_in[0];
    const float* conv_w   = (const float*)d_in[1];
    const float* conv_b   = (const float*)d_in[2];
    const float* fc_hid_w = (const float*)d_in[3];
    const float* fc_hid_b = (const float*)d_in[4];
    const float* fc_out_w = (const float*)d_in[5];
    const float* fc_out_b = (const float*)d_in[6];
    float* out = (float*)d_out;

    const int grid = (BB * TT) / 256;   // 2048 blocks, 256 positions each, ONE dispatch
    rvt_one<<<grid, 256, 0, stream>>>(x, conv_w, conv_b, fc_hid_w, fc_hid_b,
                                      fc_out_w, fc_out_b, out);
}